// Round 10
// baseline (185.954 us; speedup 1.0000x reference)
//
#include <hip/hip_runtime.h>

// ---------------------------------------------------------------------------
// DigitConvolutionalModel: x(32768,784) -> conv3x3(valid) -> 676
//   -> relu(@W1(676,300)+b1) -> relu(@W2(300,300)+b2) -> @W3(300,10)+b3
//
// R16 = R12 (verified 181.2us) + two deltas ONLY:
//  1) B privatized per wave: each wave global_load_lds-stages its own (3|2)
//     n-tile groups (same 20 groups/block, same traffic) and waits on its
//     OWN counted vmcnt -> B needs no barrier.
//  2) Barriers only at x-band edges: 13 instead of 25. Mid-band waits are
//     per-wave vmcnt(5|4); band-11 4|3; edges vmcnt(3|2)+lgkmcnt(0).
//  Theory: R12<->R14 showed latency-bound barrier convoy (16 waves all
//  parked at one program point 25x/kernel). Fewer convoy points + per-wave
//  self-pacing -> waves drift, MFMA/mem overlap across waves (m114).
//  Everything else (x f32 band staging w/ source-XOR swizzle, AFRAG+cvt,
//  tail GEMM2/3, prep) is R12 VERBATIM. No pf registers (R15's risk), no
//  new divergence. LDS 72KB -> 2 blocks/CU. Tripwire: WRITE_SIZE ~1.3MB.
// ---------------------------------------------------------------------------

typedef __bf16 bf16_t;
typedef __bf16 bf16x8 __attribute__((ext_vector_type(8)));
typedef float  f32x4  __attribute__((ext_vector_type(4)));

#define MFMA16(a, b, c) __builtin_amdgcn_mfma_f32_16x16x32_bf16((a), (b), (c), 0, 0, 0)

#define W1F_ELEMS (25 * 20 * 64 * 8)  // 256000  (K=800, N=320)
#define W2F_ELEMS (10 * 20 * 64 * 8)  // 102400  (K=320, N=320)
#define W3F_ELEMS (10 * 1 * 64 * 8)   // 5120    (K=320, N=16)

#define XSLOT 16384   // one x band: 64 rows x 256B (64 f32 cols)
#define XBASE 40960   // Bbuf = 2 * 1280 frags * 16B

// ---------------------------------------------------------------------------
__global__ void prep_weights(const float* __restrict__ conv_w,
                             const float* __restrict__ W1,
                             const float* __restrict__ W2,
                             const float* __restrict__ W3,
                             bf16_t* __restrict__ W1f,
                             bf16_t* __restrict__ W2f,
                             bf16_t* __restrict__ W3f) {
    int idx = blockIdx.x * 256 + threadIdx.x;
    if (idx < 800 * 320) {
        int k = idx / 320;
        int n = idx - k * 320;
        float v = 0.0f;
        if (k < 784 && n < 300) {
            int py = k / 28;
            int px = k - py * 28;
#pragma unroll
            for (int ky = 0; ky < 3; ++ky) {
                int oy = py - ky;
                if (oy < 0 || oy > 25) continue;
#pragma unroll
                for (int kx = 0; kx < 3; ++kx) {
                    int ox = px - kx;
                    if (ox < 0 || ox > 25) continue;
                    v += conv_w[ky * 3 + kx] * W1[(oy * 26 + ox) * 300 + n];
                }
            }
        }
        int kc = k >> 5, quad = (k >> 3) & 3, j = k & 7;
        int nt = n >> 4, nin = n & 15;
        W1f[(((kc * 20 + nt) * 64 + quad * 16 + nin) << 3) + j] = (bf16_t)v;
    } else if (idx < 800 * 320 + 320 * 320) {
        int i2 = idx - 800 * 320;
        int k = i2 / 320;
        int n = i2 - k * 320;
        float v = (k < 300 && n < 300) ? W2[k * 300 + n] : 0.0f;
        int kc = k >> 5, quad = (k >> 3) & 3, j = k & 7;
        int nt = n >> 4, nin = n & 15;
        W2f[(((kc * 20 + nt) * 64 + quad * 16 + nin) << 3) + j] = (bf16_t)v;
    } else if (idx < 800 * 320 + 320 * 320 + 320 * 16) {
        int i3 = idx - (800 * 320 + 320 * 320);
        int k = i3 / 16;
        int n = i3 - k * 16;
        float v = (k < 300 && n < 10) ? W3[k * 10 + n] : 0.0f;
        int kc = k >> 5, quad = (k >> 3) & 3, j = k & 7;
        W3f[(((kc * 64) + quad * 16 + n) << 3) + j] = (bf16_t)v;
    }
}

// async global -> LDS, 16B/lane; LDS base wave-uniform, global addr per-lane.
__device__ __forceinline__ void stage16(const void* g, void* l) {
    __builtin_amdgcn_global_load_lds(
        (const __attribute__((address_space(1))) void*)g,
        (__attribute__((address_space(3))) void*)l, 16, 0, 0);
}

// ---------------------------------------------------------------------------
// Fused kernel. Block = 64 rows, 512 thr (8 waves). Wave w: 4 m-tiles x
// (3|2) n-tiles. B private-per-wave dbuf; x f32 bands ring-2 (R12 layout).
// ---------------------------------------------------------------------------
__global__ __launch_bounds__(512, 4) void fused_mlp(
    const float* __restrict__ x, const float* __restrict__ b1,
    const float* __restrict__ b2, const float* __restrict__ b3,
    const bf16x8* __restrict__ W1f, const bf16x8* __restrict__ W2f,
    const bf16x8* __restrict__ W3f, float* __restrict__ out) {
    __shared__ __align__(16) unsigned char smem[XBASE + 2 * XSLOT];  // 72 KB
    bf16x8* Bb   = (bf16x8*)smem;  // [2][20][64] B chunk dbuf (private rgns)
    bf16x8* hbuf = (bf16x8*)smem;  // 40 KB overlay after G1
    bf16_t* hb   = (bf16_t*)smem;

    const int tid = threadIdx.x;
    const int w   = tid >> 6;
    const int l   = tid & 63;
    const int q   = l >> 4;
    const int l15 = l & 15;
    const int r0  = blockIdx.x * 64;

    const bool t3    = (w < 4);
    const int  nt0   = t3 ? (w * 3) : (12 + (w - 4) * 2);
    const int  boff2 = t3 ? 128 : 64;

    f32x4 acc[4][3];
#pragma unroll
    for (int m = 0; m < 4; ++m)
#pragma unroll
        for (int j = 0; j < 3; ++j) acc[m][j] = (f32x4){0.f, 0.f, 0.f, 0.f};

    // ---- PRIVATE B staging: wave stages ONLY its own (3|2) groups --------
#define STAGE_BP(KC, BUF)                                                      \
    {                                                                          \
        const bf16x8* ws_ = W1f + (size_t)(KC)*1280 + nt0 * 64 + l;            \
        bf16x8* wd_ = Bb + (BUF)*1280 + nt0 * 64;                              \
        stage16(ws_, wd_);                                                     \
        stage16(ws_ + 64, wd_ + 64);                                           \
        if (t3) stage16(ws_ + 128, wd_ + 128);                                 \
    }

    // ---- x band staging (R12 verbatim): 64 f32 cols, src-XOR swizzle -----
#define STAGE_BAND(BAND)                                                       \
    {                                                                          \
        unsigned char* slot_ = smem + XBASE + ((BAND)&1) * XSLOT;              \
        if ((BAND) < 12) {                                                     \
            _Pragma("unroll")                                                  \
            for (int i_ = 0; i_ < 2; ++i_) {                                   \
                int row_ = w * 8 + i_ * 4 + (l >> 4);                          \
                int u_   = (l & 15) ^ (row_ & 7);                              \
                stage16(x + (size_t)(r0 + row_) * 784 + (BAND)*64 + u_ * 4,    \
                        slot_ + w * 2048 + i_ * 1024);                         \
            }                                                                  \
        } else {                                                               \
            int row_ = w * 8 + (l >> 3);                                       \
            int u_   = (l & 7) ^ (row_ & 7);                                   \
            const float* src_ = x + (size_t)(r0 + row_) * 784 +                \
                                ((u_ < 4) ? (768 + u_ * 4) : 0);               \
            stage16(src_, slot_ + w * 1024);                                   \
        }                                                                      \
    }

    // ---- A fragment (R12 verbatim): 2x ds_read_b128 f32 + cvt ------------
#define AFRAG(DST, SLOT, RS, KCL, MT)                                          \
    {                                                                          \
        int row_ = (MT)*16 + l15;                                              \
        int r7_  = row_ & 7;                                                   \
        float4 fa_ = *(const float4*)((SLOT) + row_ * (RS) +                   \
                     ((((KCL)*8 + q * 2 + 0) ^ r7_) << 4));                    \
        float4 fb_ = *(const float4*)((SLOT) + row_ * (RS) +                   \
                     ((((KCL)*8 + q * 2 + 1) ^ r7_) << 4));                    \
        bf16x8 t_;                                                             \
        t_[0] = (bf16_t)fa_.x; t_[1] = (bf16_t)fa_.y;                          \
        t_[2] = (bf16_t)fa_.z; t_[3] = (bf16_t)fa_.w;                          \
        t_[4] = (bf16_t)fb_.x; t_[5] = (bf16_t)fb_.y;                          \
        t_[6] = (bf16_t)fb_.z; t_[7] = (bf16_t)fb_.w;                          \
        DST = t_;                                                              \
    }

#define G1CHUNK(SLOT, RS, KCL, BUF)                                            \
    {                                                                          \
        bf16x8 a0, a1, a2, a3;                                                 \
        AFRAG(a0, SLOT, RS, KCL, 0) AFRAG(a1, SLOT, RS, KCL, 1)                \
        AFRAG(a2, SLOT, RS, KCL, 2) AFRAG(a3, SLOT, RS, KCL, 3)                \
        const bf16x8* bb_ = Bb + (BUF)*1280 + nt0 * 64 + l;                    \
        bf16x8 b0 = bb_[0], b1v = bb_[64], b2v = bb_[boff2];                   \
        acc[0][0] = MFMA16(a0, b0, acc[0][0]);                                 \
        acc[1][0] = MFMA16(a1, b0, acc[1][0]);                                 \
        acc[2][0] = MFMA16(a2, b0, acc[2][0]);                                 \
        acc[3][0] = MFMA16(a3, b0, acc[3][0]);                                 \
        acc[0][1] = MFMA16(a0, b1v, acc[0][1]);                                \
        acc[1][1] = MFMA16(a1, b1v, acc[1][1]);                                \
        acc[2][1] = MFMA16(a2, b1v, acc[2][1]);                                \
        acc[3][1] = MFMA16(a3, b1v, acc[3][1]);                                \
        if (t3) {                                                              \
            acc[0][2] = MFMA16(a0, b2v, acc[0][2]);                            \
            acc[1][2] = MFMA16(a1, b2v, acc[1][2]);                            \
            acc[2][2] = MFMA16(a2, b2v, acc[2][2]);                            \
            acc[3][2] = MFMA16(a3, b2v, acc[3][2]);                            \
        }                                                                      \
    }

#define VMW(N)   asm volatile("s_waitcnt vmcnt(" #N ")" ::: "memory")
#define VMWLG(N) asm volatile("s_waitcnt vmcnt(" #N ") lgkmcnt(0)" ::: "memory")
#define SCHED0() __builtin_amdgcn_sched_barrier(0)
#define BARRIER()                         \
    __builtin_amdgcn_s_barrier();         \
    SCHED0()

    // ---------------- GEMM1: 13 bands; barriers ONLY at band edges ---------
    // prologue (cold): own B(0) + band 0, full drain.
    STAGE_BP(0, 0)
    STAGE_BAND(0)
    VMWLG(0);
    BARRIER();

    for (int b = 0; b <= 10; ++b) {
        unsigned char* xs = smem + XBASE + (b & 1) * XSLOT;
        const int k0 = 2 * b;
        // c0: stage own B(k0+1) + band b+1; wait own B(k0) (counted)
        STAGE_BP(k0 + 1, 1)
        STAGE_BAND(b + 1)
        if (t3) { VMW(5); } else { VMW(4); }
        SCHED0();
        G1CHUNK(xs, 256, 0, 0)
        // c1: stage own B(k0+2); wait own B(k0+1)
        STAGE_BP(k0 + 2, 0)
        if (t3) { VMW(5); } else { VMW(4); }
        SCHED0();
        G1CHUNK(xs, 256, 1, 1)
        // band edge: own band-(b+1) staging done; B(k0+2) stays in flight
        if (t3) { VMWLG(3); } else { VMWLG(2); }
        BARRIER();
    }
    // band 11 (chunks 22, 23): stages band 12 (1 op)
    {
        unsigned char* xs = smem + XBASE + XSLOT;  // slot 1
        STAGE_BP(23, 1)
        STAGE_BAND(12)
        if (t3) { VMW(4); } else { VMW(3); }
        SCHED0();
        G1CHUNK(xs, 256, 0, 0)
        STAGE_BP(24, 0)
        if (t3) { VMW(4); } else { VMW(3); }
        SCHED0();
        G1CHUNK(xs, 256, 1, 1)
        if (t3) { VMWLG(3); } else { VMWLG(2); }
        BARRIER();
    }
    // band 12 (chunk 24, 32 cols, row stride 128; slot 0)
    {
        unsigned char* xs = smem + XBASE;
        VMW(0);
        SCHED0();
        G1CHUNK(xs, 128, 0, 0)
        asm volatile("s_waitcnt lgkmcnt(0)" ::: "memory");
        BARRIER();  // all B/x reads done before hbuf overlay
    }

    // ---------------- h1 = relu(C1+b1) -> hbuf (A-frag order) --------------
#define HSTORE(J, BIAS)                                                        \
    {                                                                          \
        int n = (nt0 + (J)) * 16 + l15;                                        \
        float bias = (n < 300) ? (BIAS)[n] : 0.0f;                             \
        int kh = n >> 5, quad = (n >> 3) & 3, jj = n & 7;                      \
        _Pragma("unroll")                                                      \
        for (int mt = 0; mt < 4; ++mt)                                         \
            _Pragma("unroll")                                                  \
            for (int r = 0; r < 4; ++r) {                                      \
                float v = acc[mt][(J)][r] + bias;                              \
                v = v > 0.f ? v : 0.f;                                         \
                hb[(((kh * 4 + mt) * 64 + quad * 16 + q * 4 + r) << 3) + jj] = \
                    (bf16_t)v;                                                 \
            }                                                                  \
    }

    HSTORE(0, b1)
    HSTORE(1, b1)
    if (t3) HSTORE(2, b1)
    asm volatile("s_waitcnt lgkmcnt(0)" ::: "memory");
    BARRIER();  // h1 visible

    // ---------------- GEMM2: barrier-free; W2f frags from global (L2) ------
#pragma unroll
    for (int m = 0; m < 4; ++m)
#pragma unroll
        for (int j = 0; j < 3; ++j) acc[m][j] = (f32x4){0.f, 0.f, 0.f, 0.f};

    const bf16x8* bB2 = W2f + nt0 * 64 + l;

#define G2CHUNK(KC2)                                                           \
    {                                                                          \
        bf16x8 a0 = hbuf[((KC2)*4 + 0) * 64 + l];                              \
        bf16x8 a1 = hbuf[((KC2)*4 + 1) * 64 + l];                              \
        bf16x8 a2 = hbuf[((KC2)*4 + 2) * 64 + l];                              \
        bf16x8 a3 = hbuf[((KC2)*4 + 3) * 64 + l];                              \
        const bf16x8* bp = bB2 + (KC2)*1280;                                   \
        bf16x8 b0 = bp[0], b1v = bp[64], b2v = bp[boff2];                      \
        acc[0][0] = MFMA16(a0, b0, acc[0][0]);                                 \
        acc[1][0] = MFMA16(a1, b0, acc[1][0]);                                 \
        acc[2][0] = MFMA16(a2, b0, acc[2][0]);                                 \
        acc[3][0] = MFMA16(a3, b0, acc[3][0]);                                 \
        acc[0][1] = MFMA16(a0, b1v, acc[0][1]);                                \
        acc[1][1] = MFMA16(a1, b1v, acc[1][1]);                                \
        acc[2][1] = MFMA16(a2, b1v, acc[2][1]);                                \
        acc[3][1] = MFMA16(a3, b1v, acc[3][1]);                                \
        if (t3) {                                                              \
            acc[0][2] = MFMA16(a0, b2v, acc[0][2]);                            \
            acc[1][2] = MFMA16(a1, b2v, acc[1][2]);                            \
            acc[2][2] = MFMA16(a2, b2v, acc[2][2]);                            \
            acc[3][2] = MFMA16(a3, b2v, acc[3][2]);                            \
        }                                                                      \
    }

    G2CHUNK(0) G2CHUNK(1) G2CHUNK(2) G2CHUNK(3) G2CHUNK(4)
    G2CHUNK(5) G2CHUNK(6) G2CHUNK(7) G2CHUNK(8) G2CHUNK(9)

    asm volatile("s_waitcnt lgkmcnt(0)" ::: "memory");
    BARRIER();  // h1 reads done before h2 overwrite

    // ---------------- h2 = relu(C2+b2) -> hbuf -----------------------------
    HSTORE(0, b2)
    HSTORE(1, b2)
    if (t3) HSTORE(2, b2)
    asm volatile("s_waitcnt lgkmcnt(0)" ::: "memory");
    BARRIER();  // h2 visible

    // ---------------- GEMM3: waves 0-3 (mt=w); W3f frags from global -------
    if (w < 4) {
        f32x4 acc3 = (f32x4){0.f, 0.f, 0.f, 0.f};
#pragma unroll
        for (int kc3 = 0; kc3 < 10; ++kc3)
            acc3 = MFMA16(hbuf[(kc3 * 4 + w) * 64 + l], W3f[kc3 * 64 + l], acc3);
        if (l15 < 10) {
            float bias = b3[l15];
#pragma unroll
            for (int r = 0; r < 4; ++r)
                out[(size_t)(r0 + w * 16 + q * 4 + r) * 10 + l15] = acc3[r] + bias;
        }
    }
}

// ---------------------------------------------------------------------------
extern "C" void kernel_launch(void* const* d_in, const int* in_sizes, int n_in,
                              void* d_out, int out_size, void* d_ws, size_t ws_size,
                              hipStream_t stream) {
    const float* x      = (const float*)d_in[0];
    const float* conv_w = (const float*)d_in[1];
    const float* W1     = (const float*)d_in[2];
    const float* b1     = (const float*)d_in[3];
    const float* W2     = (const float*)d_in[4];
    const float* b2     = (const float*)d_in[5];
    const float* W3     = (const float*)d_in[6];
    const float* b3     = (const float*)d_in[7];
    float* out = (float*)d_out;

    char* ws = (char*)d_ws;
    bf16_t* W1f = (bf16_t*)(ws);
    bf16_t* W2f = (bf16_t*)(ws + (size_t)W1F_ELEMS * 2);
    bf16_t* W3f = (bf16_t*)(ws + (size_t)(W1F_ELEMS + W2F_ELEMS) * 2);
    if (ws_size < (size_t)(W1F_ELEMS + W2F_ELEMS + W3F_ELEMS) * 2) return;

    int prep_total = 800 * 320 + 320 * 320 + 320 * 16;  // 363520
    prep_weights<<<(prep_total + 255) / 256, 256, 0, stream>>>(
        conv_w, W1, W2, W3, W1f, W2f, W3f);

    fused_mlp<<<32768 / 64, 512, 0, stream>>>(
        x, b1, b2, b3, (const bf16x8*)W1f, (const bf16x8*)W2f,
        (const bf16x8*)W3f, out);
}